// Round 2
// baseline (1950.673 us; speedup 1.0000x reference)
//
#include <hip/hip_runtime.h>
#include <stdint.h>

// Sparse 5x5x5 conv (N=500k, 32->32ch, 125 taps) + BatchNorm + ELU + Linear.
// R4: back to the R2 register-double-bank gather pipeline (412us), with the
// occupancy cap removed: __launch_bounds__(256,4) -> 4 blocks/CU (16 waves/CU,
// ~2x in-flight gathers vs the (256,2) version; VGPR was 96, budget 128).
// nbr index loads are one dwordx4 per tile per 16-tap window (from R3).

#define NV 500000
#define KT 125
#define CH 32
#define EPSBN 1e-5f
#define NTILES (NV / 16)   // 31250

typedef __attribute__((ext_vector_type(8))) short short8;   // 8 x bf16 frag
typedef __attribute__((ext_vector_type(4))) float f32x4;    // MFMA C/D frag
typedef __attribute__((ext_vector_type(4), aligned(4))) int int4a; // dword-aligned int4

__device__ __forceinline__ unsigned short f2bf(float f) {
    union { float f; unsigned int u; } v; v.f = f;
    unsigned int u = v.u;
    return (unsigned short)((u + 0x7fffu + ((u >> 16) & 1u)) >> 16);  // RNE
}

// K1: x -> bf16 (vectorized); W_conv B-frags (wf); W_lin^T B-frags (wl); zero stats.
// wf frag(k, h, lane, j) = W_conv[k][ (lane>>4)*8 + j ][ h*16 + (lane&15) ]
// wl frag(h, lane, j)    = W_lin [ h*16 + (lane&15) ][ (lane>>4)*8 + j ]
__global__ __launch_bounds__(256) void
k_prep(const float* __restrict__ x, const float* __restrict__ Wc,
       const float* __restrict__ Wlin,
       unsigned short* __restrict__ xb, unsigned short* __restrict__ wf,
       unsigned short* __restrict__ wl, float* __restrict__ stats) {
    int tid = blockIdx.x * blockDim.x + threadIdx.x;
    if (blockIdx.x == 0 && threadIdx.x < 64) stats[threadIdx.x] = 0.0f;
    if (tid < KT * 2 * 64) {
        int k = tid >> 7;
        int rem = tid & 127;
        int h = rem >> 6;
        int l = rem & 63;
        int kd0 = (l >> 4) * 8;
        int cc = h * 16 + (l & 15);
        #pragma unroll
        for (int j = 0; j < 8; j++)
            wf[tid * 8 + j] = f2bf(Wc[(k * CH + kd0 + j) * CH + cc]);
    } else if (tid < KT * 2 * 64 + 128) {
        int t2 = tid - KT * 2 * 64;
        int h = t2 >> 6;
        int l = t2 & 63;
        int n = l & 15;
        int kd0 = (l >> 4) * 8;
        #pragma unroll
        for (int j = 0; j < 8; j++)
            wl[t2 * 8 + j] = f2bf(Wlin[(h * 16 + n) * CH + kd0 + j]);
    }
    size_t i8 = (size_t)tid * 8;
    if (i8 < (size_t)NV * CH) {
        float4 a = *(const float4*)(x + i8);
        float4 b = *(const float4*)(x + i8 + 4);
        short8 o;
        o[0] = (short)f2bf(a.x); o[1] = (short)f2bf(a.y);
        o[2] = (short)f2bf(a.z); o[3] = (short)f2bf(a.w);
        o[4] = (short)f2bf(b.x); o[5] = (short)f2bf(b.y);
        o[6] = (short)f2bf(b.z); o[7] = (short)f2bf(b.w);
        *(short8*)(xb + i8) = o;
    }
}

// ---- k_conv pipeline helpers (all force-inlined, constant-folded) ----

// One dwordx4 per tile: lane(q) holds window taps [q*4 .. q*4+3] for its row m.
// Window 7 reads up to tap index 127 (3 ints past row end); only the final
// voxel row can cross the buffer end by 12B -- stays within the last page,
// and the values are masked (k>124 -> idx=-1) before use.
__device__ __forceinline__ void
load_nb4(int wl, const int* __restrict__ nbr, const int (&rbase)[4], int q4,
         int4a (&out)[4]) {
    #pragma unroll
    for (int t = 0; t < 4; t++)
        out[t] = *(const int4a*)(nbr + rbase[t] + wl * 16 + q4);
}

// Refill bank BANK with the 2-tap group whose window-local first tap is C0
// (compile-time) and global first tap is k0 (runtime; taps >124 masked).
// Tap c of the window lives in element (c&3) of lane ((c>>2)<<4)|m.
template<int BANK, int C0>
__device__ __forceinline__ void
refill(short8 (&A)[2][2][4], short8 (&B)[2][2][2], int k0, const int4a (&nb)[4],
       const unsigned short* __restrict__ xb, const unsigned short* __restrict__ wf,
       int m, int q, int lane) {
    #pragma unroll
    for (int jj = 0; jj < 2; jj++) {
        const int c = C0 + jj;                    // compile-time
        int k = k0 + jj;                          // runtime
        int kc = k > 124 ? 124 : k;
        B[BANK][jj][0] = *(const short8*)(wf + (size_t)(kc * 128 + lane) * 8);
        B[BANK][jj][1] = *(const short8*)(wf + (size_t)(kc * 128 + 64 + lane) * 8);
        #pragma unroll
        for (int t = 0; t < 4; t++) {
            int idx = __shfl(nb[t][c & 3], ((c >> 2) << 4) | m, 64);
            if (k > 124) idx = -1;
            short8 a = {0, 0, 0, 0, 0, 0, 0, 0};
            if (idx >= 0) a = *(const short8*)(xb + (size_t)idx * CH + q * 8);
            A[BANK][jj][t] = a;
        }
    }
}

template<int BANK>
__device__ __forceinline__ void
consume(f32x4 (&acc)[4][2], const short8 (&A)[2][2][4], const short8 (&B)[2][2][2]) {
    #pragma unroll
    for (int jj = 0; jj < 2; jj++) {
        #pragma unroll
        for (int t = 0; t < 4; t++) {
            acc[t][0] = __builtin_amdgcn_mfma_f32_16x16x32_bf16(A[BANK][jj][t], B[BANK][jj][0], acc[t][0], 0, 0, 0);
            acc[t][1] = __builtin_amdgcn_mfma_f32_16x16x32_bf16(A[BANK][jj][t], B[BANK][jj][1], acc[t][1], 0, 0, 0);
        }
    }
}

// K2: gather-conv. Wave = 4 tiles of 16 voxels. Taps padded to 128, processed
// as 8 windows x 8 groups(2 taps), double-buffered refill distance 2.
__global__ __launch_bounds__(256, 4) void
k_conv(const unsigned short* __restrict__ xb, const int* __restrict__ nbr,
       const unsigned short* __restrict__ wf, float* __restrict__ co,
       float* __restrict__ stats) {
    const int lane = threadIdx.x & 63;
    const int wv = threadIdx.x >> 6;
    const int m = lane & 15;
    const int q = lane >> 4;
    const int q4 = q * 4;
    const int vbase = (blockIdx.x * 4 + wv) * 64;

    f32x4 acc[4][2];
    #pragma unroll
    for (int t = 0; t < 4; t++)
        #pragma unroll
        for (int h = 0; h < 2; h++)
            acc[t][h] = f32x4{0.f, 0.f, 0.f, 0.f};

    bool tval[4];
    int rbase[4];
    #pragma unroll
    for (int t = 0; t < 4; t++) {
        tval[t] = (vbase + t * 16) < NV;
        rbase[t] = tval[t] ? (vbase + t * 16 + m) * KT : 0;
    }

    short8 A[2][2][4];
    short8 B[2][2][2];
    int4a nb4[4], nbn4[4];

    load_nb4(0, nbr, rbase, q4, nb4);
    refill<0, 0>(A, B, 0, nb4, xb, wf, m, q, lane);
    refill<1, 2>(A, B, 2, nb4, xb, wf, m, q, lane);

    for (int w = 0; w < 8; w++) {
        const int kb = w * 16;
        if (w < 7) load_nb4(w + 1, nbr, rbase, q4, nbn4);
        consume<0>(acc, A, B); refill<0, 4>(A, B, kb + 4, nb4, xb, wf, m, q, lane);
        consume<1>(acc, A, B); refill<1, 6>(A, B, kb + 6, nb4, xb, wf, m, q, lane);
        consume<0>(acc, A, B); refill<0, 8>(A, B, kb + 8, nb4, xb, wf, m, q, lane);
        consume<1>(acc, A, B); refill<1, 10>(A, B, kb + 10, nb4, xb, wf, m, q, lane);
        consume<0>(acc, A, B); refill<0, 12>(A, B, kb + 12, nb4, xb, wf, m, q, lane);
        consume<1>(acc, A, B); refill<1, 14>(A, B, kb + 14, nb4, xb, wf, m, q, lane);
        consume<0>(acc, A, B); refill<0, 0>(A, B, kb + 16, nbn4, xb, wf, m, q, lane);
        consume<1>(acc, A, B); refill<1, 2>(A, B, kb + 18, nbn4, xb, wf, m, q, lane);
        #pragma unroll
        for (int t = 0; t < 4; t++)
            nb4[t] = nbn4[t];
    }

    float s0 = 0.f, s1 = 0.f, q0 = 0.f, q1 = 0.f;
    #pragma unroll
    for (int t = 0; t < 4; t++) {
        if (!tval[t]) continue;
        int v0 = vbase + t * 16 + q * 4;
        #pragma unroll
        for (int r = 0; r < 4; r++) {
            float a0 = acc[t][0][r], a1 = acc[t][1][r];
            co[(size_t)(v0 + r) * CH + m] = a0;
            co[(size_t)(v0 + r) * CH + 16 + m] = a1;
            s0 += a0; q0 += a0 * a0;
            s1 += a1; q1 += a1 * a1;
        }
    }
    s0 += __shfl_xor(s0, 16); s0 += __shfl_xor(s0, 32);
    s1 += __shfl_xor(s1, 16); s1 += __shfl_xor(s1, 32);
    q0 += __shfl_xor(q0, 16); q0 += __shfl_xor(q0, 32);
    q1 += __shfl_xor(q1, 16); q1 += __shfl_xor(q1, 32);
    if (q == 0) {
        atomicAdd(&stats[m],      s0);
        atomicAdd(&stats[16 + m], s1);
        atomicAdd(&stats[32 + m], q0);
        atomicAdd(&stats[48 + m], q1);
    }
}

// K3: finalize BN scale/shift. stats[64..95]=scale, stats[96..127]=shift.
__global__ void k_final(const float* __restrict__ gamma, const float* __restrict__ beta,
                        float* __restrict__ stats) {
    int c = threadIdx.x;
    if (c < CH) {
        float mean = stats[c] * (1.0f / NV);
        float var = stats[32 + c] * (1.0f / NV) - mean * mean;
        float sc = gamma[c] * rsqrtf(var + EPSBN);
        stats[64 + c] = sc;
        stats[96 + c] = beta[c] - mean * sc;
    }
}

// K4: in-place BN + ELU + MFMA linear on d_out. Wave = one 16-voxel tile/iter.
// Load layout lane(m,q) <- row v0+m, ch q*8..+8 == A-fragment layout exactly.
__global__ __launch_bounds__(256) void
k_epi(float* __restrict__ io, const unsigned short* __restrict__ wl,
      const float* __restrict__ blin, const float* __restrict__ stats) {
    const int lane = threadIdx.x & 63;
    const int wv = threadIdx.x >> 6;
    const int m = lane & 15;
    const int q = lane >> 4;

    short8 wl0 = *(const short8*)(wl + (size_t)lane * 8);
    short8 wl1 = *(const short8*)(wl + (size_t)(64 + lane) * 8);
    float ssc8[8], ssh8[8];
    #pragma unroll
    for (int j = 0; j < 8; j++) {
        ssc8[j] = stats[64 + q * 8 + j];
        ssh8[j] = stats[96 + q * 8 + j];
    }
    float bias0 = blin[m];
    float bias1 = blin[16 + m];

    const int wstep = gridDim.x * 4;
    for (int tile = blockIdx.x * 4 + wv; tile < NTILES; tile += wstep) {
        const int v0 = tile * 16;
        const float* p = io + (size_t)(v0 + m) * CH + q * 8;
        float4 e0 = *(const float4*)p;
        float4 e1 = *(const float4*)(p + 4);
        float e[8] = {e0.x, e0.y, e0.z, e0.w, e1.x, e1.y, e1.z, e1.w};
        short8 a;
        #pragma unroll
        for (int j = 0; j < 8; j++) {
            float f = e[j] * ssc8[j] + ssh8[j];
            f = f > 0.0f ? f : (__expf(f) - 1.0f);      // ELU alpha=1
            a[j] = (short)f2bf(f);
        }
        f32x4 z = {0.f, 0.f, 0.f, 0.f};
        f32x4 d0 = __builtin_amdgcn_mfma_f32_16x16x32_bf16(a, wl0, z, 0, 0, 0);
        f32x4 d1 = __builtin_amdgcn_mfma_f32_16x16x32_bf16(a, wl1, z, 0, 0, 0);
        #pragma unroll
        for (int r = 0; r < 4; r++) {
            io[(size_t)(v0 + q * 4 + r) * CH + m]      = d0[r] + bias0;
            io[(size_t)(v0 + q * 4 + r) * CH + 16 + m] = d1[r] + bias1;
        }
    }
}

extern "C" void kernel_launch(void* const* d_in, const int* in_sizes, int n_in,
                              void* d_out, int out_size, void* d_ws, size_t ws_size,
                              hipStream_t stream) {
    const float* x     = (const float*)d_in[0];
    const int*   nbr   = (const int*)d_in[1];
    const float* Wc    = (const float*)d_in[2];
    // d_in[3] = b_conv: canceled by BN mean subtraction.
    const float* gamma = (const float*)d_in[4];
    const float* beta  = (const float*)d_in[5];
    const float* Wlin  = (const float*)d_in[6];
    const float* blin  = (const float*)d_in[7];
    float* out = (float*)d_out;

    char* ws = (char*)d_ws;
    unsigned short* xb = (unsigned short*)ws;                               // 32 MB
    size_t off = (size_t)NV * CH * 2;
    unsigned short* wf = (unsigned short*)(ws + off);                       // 256 KB
    off += (size_t)KT * 128 * 8 * 2;
    unsigned short* wl = (unsigned short*)(ws + off);                       // 2 KB
    off += 128 * 8 * 2;
    float* stats = (float*)(ws + off);                                      // 512 B

    int prep_blocks = (int)(((size_t)NV * CH / 8 + 255) / 256);             // 7813
    hipLaunchKernelGGL(k_prep, dim3(prep_blocks), dim3(256), 0, stream,
                       x, Wc, Wlin, xb, wf, wl, stats);
    hipLaunchKernelGGL(k_conv, dim3((NV + 255) / 256), dim3(256), 0, stream,
                       xb, nbr, wf, out, stats);
    hipLaunchKernelGGL(k_final, dim3(1), dim3(64), 0, stream, gamma, beta, stats);
    hipLaunchKernelGGL(k_epi, dim3(1024), dim3(256), 0, stream, out, wl, blin, stats);
}

// Round 3
// 772.297 us; speedup vs baseline: 2.5258x; 2.5258x over previous
//
#include <hip/hip_runtime.h>
#include <stdint.h>

// Sparse 5x5x5 conv (N=500k, 32->32ch, 125 taps) + BatchNorm + ELU + Linear.
// R5: R2 register-bank gather pipeline, deepened. 4 A-banks (refill distance
// 3 groups => 1.5x outstanding gathers/wave vs R2) + just-in-time 2-bank B
// (weight frags are L2-hits; distance 1 suffices; saves 32 VGPRs).
// __launch_bounds__(256,2) kept -- R4 proved (256,4) makes the allocator
// squeeze to 64 VGPR and spill (FETCH/WRITE ballooned +2.3GB each).
// Spill canary for this round: WRITE_SIZE must stay ~64MB.

#define NV 500000
#define KT 125
#define CH 32
#define EPSBN 1e-5f
#define NTILES (NV / 16)   // 31250

typedef __attribute__((ext_vector_type(8))) short short8;   // 8 x bf16 frag
typedef __attribute__((ext_vector_type(4))) float f32x4;    // MFMA C/D frag
typedef __attribute__((ext_vector_type(4), aligned(4))) int int4a; // dword-aligned int4

__device__ __forceinline__ unsigned short f2bf(float f) {
    union { float f; unsigned int u; } v; v.f = f;
    unsigned int u = v.u;
    return (unsigned short)((u + 0x7fffu + ((u >> 16) & 1u)) >> 16);  // RNE
}

// K1: x -> bf16 (vectorized); W_conv B-frags (wf); W_lin^T B-frags (wl); zero stats.
__global__ __launch_bounds__(256) void
k_prep(const float* __restrict__ x, const float* __restrict__ Wc,
       const float* __restrict__ Wlin,
       unsigned short* __restrict__ xb, unsigned short* __restrict__ wf,
       unsigned short* __restrict__ wl, float* __restrict__ stats) {
    int tid = blockIdx.x * blockDim.x + threadIdx.x;
    if (blockIdx.x == 0 && threadIdx.x < 64) stats[threadIdx.x] = 0.0f;
    if (tid < KT * 2 * 64) {
        int k = tid >> 7;
        int rem = tid & 127;
        int h = rem >> 6;
        int l = rem & 63;
        int kd0 = (l >> 4) * 8;
        int cc = h * 16 + (l & 15);
        #pragma unroll
        for (int j = 0; j < 8; j++)
            wf[tid * 8 + j] = f2bf(Wc[(k * CH + kd0 + j) * CH + cc]);
    } else if (tid < KT * 2 * 64 + 128) {
        int t2 = tid - KT * 2 * 64;
        int h = t2 >> 6;
        int l = t2 & 63;
        int n = l & 15;
        int kd0 = (l >> 4) * 8;
        #pragma unroll
        for (int j = 0; j < 8; j++)
            wl[t2 * 8 + j] = f2bf(Wlin[(h * 16 + n) * CH + kd0 + j]);
    }
    size_t i8 = (size_t)tid * 8;
    if (i8 < (size_t)NV * CH) {
        float4 a = *(const float4*)(x + i8);
        float4 b = *(const float4*)(x + i8 + 4);
        short8 o;
        o[0] = (short)f2bf(a.x); o[1] = (short)f2bf(a.y);
        o[2] = (short)f2bf(a.z); o[3] = (short)f2bf(a.w);
        o[4] = (short)f2bf(b.x); o[5] = (short)f2bf(b.y);
        o[6] = (short)f2bf(b.z); o[7] = (short)f2bf(b.w);
        *(short8*)(xb + i8) = o;
    }
}

// ---- k_conv pipeline helpers (compile-time bank/tap indices everywhere) ----

// Refill A bank BANK with gather-group (2 taps x 4 tiles). C0 = window-local
// first tap (compile-time, selects int4 component + lane group for shfl);
// k0 = global first tap (runtime; >124 masked to zero-frag).
template<int BANK, int C0>
__device__ __forceinline__ void
refillA(short8 (&A)[4][2][4], int k0, const int4a (&nb)[4],
        const unsigned short* __restrict__ xb, int m, int q) {
    #pragma unroll
    for (int jj = 0; jj < 2; jj++) {
        const int c = C0 + jj;                    // compile-time
        int k = k0 + jj;                          // runtime
        #pragma unroll
        for (int t = 0; t < 4; t++) {
            int idx = __shfl(nb[t][c & 3], ((c >> 2) << 4) | m, 64);
            if (k > 124) idx = -1;
            short8 a = {0, 0, 0, 0, 0, 0, 0, 0};
            if (idx >= 0) a = *(const short8*)(xb + (size_t)idx * CH + q * 8);
            A[BANK][jj][t] = a;
        }
    }
}

// Load weight frags for a 2-tap group into B bank BANK (L2-hit stream).
template<int BANK>
__device__ __forceinline__ void
loadB(short8 (&B)[2][2][2], int k0, const unsigned short* __restrict__ wf, int lane) {
    #pragma unroll
    for (int jj = 0; jj < 2; jj++) {
        int kc = k0 + jj;
        if (kc > 124) kc = 124;
        B[BANK][jj][0] = *(const short8*)(wf + (size_t)(kc * 128 + lane) * 8);
        B[BANK][jj][1] = *(const short8*)(wf + (size_t)(kc * 128 + 64 + lane) * 8);
    }
}

template<int AB, int BB>
__device__ __forceinline__ void
consume(f32x4 (&acc)[4][2], const short8 (&A)[4][2][4], const short8 (&B)[2][2][2]) {
    #pragma unroll
    for (int jj = 0; jj < 2; jj++) {
        #pragma unroll
        for (int t = 0; t < 4; t++) {
            acc[t][0] = __builtin_amdgcn_mfma_f32_16x16x32_bf16(A[AB][jj][t], B[BB][jj][0], acc[t][0], 0, 0, 0);
            acc[t][1] = __builtin_amdgcn_mfma_f32_16x16x32_bf16(A[AB][jj][t], B[BB][jj][1], acc[t][1], 0, 0, 0);
        }
    }
}

// K2: gather-conv. Wave = 4 tiles of 16 voxels. Taps padded to 128, processed
// as 8 windows x 8 groups(2 taps). 4 A-banks, refill distance 3; JIT B.
// Body at position P (consuming group g=8w+P): refill A bank (P+3)&3 with
// group g+3, load B bank (P+1)&1 with group g+1, then consume A[P&3] x B[P&1].
// The bank being refilled was freed one position earlier -> refill precedes
// consume, so gathers are in flight during the MFMAs.
__global__ __launch_bounds__(256, 2) void
k_conv(const unsigned short* __restrict__ xb, const int* __restrict__ nbr,
       const unsigned short* __restrict__ wf, float* __restrict__ co,
       float* __restrict__ stats) {
    const int lane = threadIdx.x & 63;
    const int wv = threadIdx.x >> 6;
    const int m = lane & 15;
    const int q = lane >> 4;
    const int q4 = q * 4;
    const int vbase = (blockIdx.x * 4 + wv) * 64;

    f32x4 acc[4][2];
    #pragma unroll
    for (int t = 0; t < 4; t++)
        #pragma unroll
        for (int h = 0; h < 2; h++)
            acc[t][h] = f32x4{0.f, 0.f, 0.f, 0.f};

    bool tval[4];
    int rbase[4];
    #pragma unroll
    for (int t = 0; t < 4; t++) {
        tval[t] = (vbase + t * 16) < NV;
        rbase[t] = tval[t] ? (vbase + t * 16 + m) * KT : 0;
    }

    short8 A[4][2][4];     // 4 gather banks   (128 VGPR)
    short8 B[2][2][2];     // 2 weight banks   (32 VGPR)
    int4a nb4[4], nbn4[4];

    // prologue: window-0 indices, A groups 0..2 into banks 0..2, B group 0.
    #pragma unroll
    for (int t = 0; t < 4; t++)
        nb4[t] = *(const int4a*)(nbr + rbase[t] + q4);
    refillA<0, 0>(A, 0, nb4, xb, m, q);
    refillA<1, 2>(A, 2, nb4, xb, m, q);
    refillA<2, 4>(A, 4, nb4, xb, m, q);
    loadB<0>(B, 0, wf, lane);

    for (int w = 0; w < 8; w++) {
        const int kb = w * 16;
        const int wo = ((w < 7) ? (w + 1) : 0) * 16;   // next-window tap offset (w=7: dummy, masked)
        // P=0
        refillA<3, 6>(A, kb + 6, nb4, xb, m, q);   loadB<1>(B, kb + 2, wf, lane);  consume<0, 0>(acc, A, B);
        // P=1
        refillA<0, 8>(A, kb + 8, nb4, xb, m, q);   loadB<0>(B, kb + 4, wf, lane);  consume<1, 1>(acc, A, B);
        // P=2
        refillA<1, 10>(A, kb + 10, nb4, xb, m, q); loadB<1>(B, kb + 6, wf, lane);  consume<2, 0>(acc, A, B);
        // P=3 (+ first half of next-window index prefetch)
        nbn4[0] = *(const int4a*)(nbr + rbase[0] + wo + q4);
        nbn4[1] = *(const int4a*)(nbr + rbase[1] + wo + q4);
        refillA<2, 12>(A, kb + 12, nb4, xb, m, q); loadB<0>(B, kb + 8, wf, lane);  consume<3, 1>(acc, A, B);
        // P=4 (+ second half)
        nbn4[2] = *(const int4a*)(nbr + rbase[2] + wo + q4);
        nbn4[3] = *(const int4a*)(nbr + rbase[3] + wo + q4);
        refillA<3, 14>(A, kb + 14, nb4, xb, m, q); loadB<1>(B, kb + 10, wf, lane); consume<0, 0>(acc, A, B);
        // P=5..7: refills come from the next window
        refillA<0, 0>(A, kb + 16, nbn4, xb, m, q); loadB<0>(B, kb + 12, wf, lane); consume<1, 1>(acc, A, B);
        refillA<1, 2>(A, kb + 18, nbn4, xb, m, q); loadB<1>(B, kb + 14, wf, lane); consume<2, 0>(acc, A, B);
        refillA<2, 4>(A, kb + 20, nbn4, xb, m, q); loadB<0>(B, kb + 16, wf, lane); consume<3, 1>(acc, A, B);
        #pragma unroll
        for (int t = 0; t < 4; t++)
            nb4[t] = nbn4[t];
    }

    float s0 = 0.f, s1 = 0.f, q0 = 0.f, q1 = 0.f;
    #pragma unroll
    for (int t = 0; t < 4; t++) {
        if (!tval[t]) continue;
        int v0 = vbase + t * 16 + q * 4;
        #pragma unroll
        for (int r = 0; r < 4; r++) {
            float a0 = acc[t][0][r], a1 = acc[t][1][r];
            co[(size_t)(v0 + r) * CH + m] = a0;
            co[(size_t)(v0 + r) * CH + 16 + m] = a1;
            s0 += a0; q0 += a0 * a0;
            s1 += a1; q1 += a1 * a1;
        }
    }
    s0 += __shfl_xor(s0, 16); s0 += __shfl_xor(s0, 32);
    s1 += __shfl_xor(s1, 16); s1 += __shfl_xor(s1, 32);
    q0 += __shfl_xor(q0, 16); q0 += __shfl_xor(q0, 32);
    q1 += __shfl_xor(q1, 16); q1 += __shfl_xor(q1, 32);
    if (q == 0) {
        atomicAdd(&stats[m],      s0);
        atomicAdd(&stats[16 + m], s1);
        atomicAdd(&stats[32 + m], q0);
        atomicAdd(&stats[48 + m], q1);
    }
}

// K3: finalize BN scale/shift. stats[64..95]=scale, stats[96..127]=shift.
__global__ void k_final(const float* __restrict__ gamma, const float* __restrict__ beta,
                        float* __restrict__ stats) {
    int c = threadIdx.x;
    if (c < CH) {
        float mean = stats[c] * (1.0f / NV);
        float var = stats[32 + c] * (1.0f / NV) - mean * mean;
        float sc = gamma[c] * rsqrtf(var + EPSBN);
        stats[64 + c] = sc;
        stats[96 + c] = beta[c] - mean * sc;
    }
}

// K4: in-place BN + ELU + MFMA linear on d_out. Wave = one 16-voxel tile/iter.
__global__ __launch_bounds__(256) void
k_epi(float* __restrict__ io, const unsigned short* __restrict__ wl,
      const float* __restrict__ blin, const float* __restrict__ stats) {
    const int lane = threadIdx.x & 63;
    const int wv = threadIdx.x >> 6;
    const int m = lane & 15;
    const int q = lane >> 4;

    short8 wl0 = *(const short8*)(wl + (size_t)lane * 8);
    short8 wl1 = *(const short8*)(wl + (size_t)(64 + lane) * 8);
    float ssc8[8], ssh8[8];
    #pragma unroll
    for (int j = 0; j < 8; j++) {
        ssc8[j] = stats[64 + q * 8 + j];
        ssh8[j] = stats[96 + q * 8 + j];
    }
    float bias0 = blin[m];
    float bias1 = blin[16 + m];

    const int wstep = gridDim.x * 4;
    for (int tile = blockIdx.x * 4 + wv; tile < NTILES; tile += wstep) {
        const int v0 = tile * 16;
        const float* p = io + (size_t)(v0 + m) * CH + q * 8;
        float4 e0 = *(const float4*)p;
        float4 e1 = *(const float4*)(p + 4);
        float e[8] = {e0.x, e0.y, e0.z, e0.w, e1.x, e1.y, e1.z, e1.w};
        short8 a;
        #pragma unroll
        for (int j = 0; j < 8; j++) {
            float f = e[j] * ssc8[j] + ssh8[j];
            f = f > 0.0f ? f : (__expf(f) - 1.0f);      // ELU alpha=1
            a[j] = (short)f2bf(f);
        }
        f32x4 z = {0.f, 0.f, 0.f, 0.f};
        f32x4 d0 = __builtin_amdgcn_mfma_f32_16x16x32_bf16(a, wl0, z, 0, 0, 0);
        f32x4 d1 = __builtin_amdgcn_mfma_f32_16x16x32_bf16(a, wl1, z, 0, 0, 0);
        #pragma unroll
        for (int r = 0; r < 4; r++) {
            io[(size_t)(v0 + q * 4 + r) * CH + m]      = d0[r] + bias0;
            io[(size_t)(v0 + q * 4 + r) * CH + 16 + m] = d1[r] + bias1;
        }
    }
}

extern "C" void kernel_launch(void* const* d_in, const int* in_sizes, int n_in,
                              void* d_out, int out_size, void* d_ws, size_t ws_size,
                              hipStream_t stream) {
    const float* x     = (const float*)d_in[0];
    const int*   nbr   = (const int*)d_in[1];
    const float* Wc    = (const float*)d_in[2];
    // d_in[3] = b_conv: canceled by BN mean subtraction.
    const float* gamma = (const float*)d_in[4];
    const float* beta  = (const float*)d_in[5];
    const float* Wlin  = (const float*)d_in[6];
    const float* blin  = (const float*)d_in[7];
    float* out = (float*)d_out;

    char* ws = (char*)d_ws;
    unsigned short* xb = (unsigned short*)ws;                               // 32 MB
    size_t off = (size_t)NV * CH * 2;
    unsigned short* wf = (unsigned short*)(ws + off);                       // 256 KB
    off += (size_t)KT * 128 * 8 * 2;
    unsigned short* wl = (unsigned short*)(ws + off);                       // 2 KB
    off += 128 * 8 * 2;
    float* stats = (float*)(ws + off);                                      // 512 B

    int prep_blocks = (int)(((size_t)NV * CH / 8 + 255) / 256);             // 7813
    hipLaunchKernelGGL(k_prep, dim3(prep_blocks), dim3(256), 0, stream,
                       x, Wc, Wlin, xb, wf, wl, stats);
    hipLaunchKernelGGL(k_conv, dim3((NV + 255) / 256), dim3(256), 0, stream,
                       xb, nbr, wf, out, stats);
    hipLaunchKernelGGL(k_final, dim3(1), dim3(64), 0, stream, gamma, beta, stats);
    hipLaunchKernelGGL(k_epi, dim3(1024), dim3(256), 0, stream, out, wl, blin, stats);
}

// Round 4
// 752.167 us; speedup vs baseline: 2.5934x; 1.0268x over previous
//
#include <hip/hip_runtime.h>
#include <stdint.h>

// Sparse 5x5x5 conv (N=500k, 32->32ch, 125 taps) + BatchNorm + ELU + Linear.
// R6: R2-structure pipeline (2 A-banks, refill distance 2, (256,2), dwordx4
// nbr loads) + NON-TEMPORAL hints on all streaming traffic (nbr loads, co
// stores, x loads). Theory: the 250MB/dispatch nbr stream + 64MB writes cycle
// the entire 256MB L3 every dispatch, evicting the 32MB xb gather image ->
// gathers fall to HBM at random-64B efficiency (~2.5 TB/s), the observed
// plateau. nt streams should leave xb L3-resident.
// Canaries: VGPR ~96-120, WRITE_SIZE ~64MB (no spill).

#define NV 500000
#define KT 125
#define CH 32
#define EPSBN 1e-5f
#define NTILES (NV / 16)   // 31250

typedef __attribute__((ext_vector_type(8))) short short8;   // 8 x bf16 frag
typedef __attribute__((ext_vector_type(4))) float f32x4;    // MFMA C/D frag
typedef __attribute__((ext_vector_type(4), aligned(4))) int int4a; // dword-aligned int4

__device__ __forceinline__ unsigned short f2bf(float f) {
    union { float f; unsigned int u; } v; v.f = f;
    unsigned int u = v.u;
    return (unsigned short)((u + 0x7fffu + ((u >> 16) & 1u)) >> 16);  // RNE
}

// K1: x -> bf16 (vectorized); W_conv B-frags (wf); W_lin^T B-frags (wl); zero stats.
__global__ __launch_bounds__(256) void
k_prep(const float* __restrict__ x, const float* __restrict__ Wc,
       const float* __restrict__ Wlin,
       unsigned short* __restrict__ xb, unsigned short* __restrict__ wf,
       unsigned short* __restrict__ wl, float* __restrict__ stats) {
    int tid = blockIdx.x * blockDim.x + threadIdx.x;
    if (blockIdx.x == 0 && threadIdx.x < 64) stats[threadIdx.x] = 0.0f;
    if (tid < KT * 2 * 64) {
        int k = tid >> 7;
        int rem = tid & 127;
        int h = rem >> 6;
        int l = rem & 63;
        int kd0 = (l >> 4) * 8;
        int cc = h * 16 + (l & 15);
        #pragma unroll
        for (int j = 0; j < 8; j++)
            wf[tid * 8 + j] = f2bf(Wc[(k * CH + kd0 + j) * CH + cc]);
    } else if (tid < KT * 2 * 64 + 128) {
        int t2 = tid - KT * 2 * 64;
        int h = t2 >> 6;
        int l = t2 & 63;
        int n = l & 15;
        int kd0 = (l >> 4) * 8;
        #pragma unroll
        for (int j = 0; j < 8; j++)
            wl[t2 * 8 + j] = f2bf(Wlin[(h * 16 + n) * CH + kd0 + j]);
    }
    size_t i8 = (size_t)tid * 8;
    if (i8 < (size_t)NV * CH) {
        // nt: x is read-once; don't let the 64MB stream evict xb from L3.
        f32x4 a = __builtin_nontemporal_load((const f32x4*)(x + i8));
        f32x4 b = __builtin_nontemporal_load((const f32x4*)(x + i8 + 4));
        short8 o;
        o[0] = (short)f2bf(a[0]); o[1] = (short)f2bf(a[1]);
        o[2] = (short)f2bf(a[2]); o[3] = (short)f2bf(a[3]);
        o[4] = (short)f2bf(b[0]); o[5] = (short)f2bf(b[1]);
        o[6] = (short)f2bf(b[2]); o[7] = (short)f2bf(b[3]);
        *(short8*)(xb + i8) = o;   // xb writes stay cached: this is the gather image
    }
}

// ---- k_conv pipeline helpers (all force-inlined, constant-folded) ----

// One nt dwordx4 per tile: lane(q) holds window taps [q*4..q*4+3] for its row m.
// Window 7 reads up to 12B past the final row; stays within the allocation's
// last page and the values are masked (k>124 -> idx=-1) before use.
__device__ __forceinline__ void
load_nb4(int wl, const int* __restrict__ nbr, const int (&rbase)[4], int q4,
         int4a (&out)[4]) {
    #pragma unroll
    for (int t = 0; t < 4; t++)
        out[t] = __builtin_nontemporal_load((const int4a*)(nbr + rbase[t] + wl * 16 + q4));
}

// Refill bank BANK with the 2-tap group whose window-local first tap is C0
// (compile-time) and global first tap is k0 (runtime; taps >124 masked).
template<int BANK, int C0>
__device__ __forceinline__ void
refill(short8 (&A)[2][2][4], short8 (&B)[2][2][2], int k0, const int4a (&nb)[4],
       const unsigned short* __restrict__ xb, const unsigned short* __restrict__ wf,
       int m, int q, int lane) {
    #pragma unroll
    for (int jj = 0; jj < 2; jj++) {
        const int c = C0 + jj;                    // compile-time
        int k = k0 + jj;                          // runtime
        int kc = k > 124 ? 124 : k;
        B[BANK][jj][0] = *(const short8*)(wf + (size_t)(kc * 128 + lane) * 8);
        B[BANK][jj][1] = *(const short8*)(wf + (size_t)(kc * 128 + 64 + lane) * 8);
        #pragma unroll
        for (int t = 0; t < 4; t++) {
            int idx = __shfl(nb[t][c & 3], ((c >> 2) << 4) | m, 64);
            if (k > 124) idx = -1;
            short8 a = {0, 0, 0, 0, 0, 0, 0, 0};
            if (idx >= 0) a = *(const short8*)(xb + (size_t)idx * CH + q * 8);
            A[BANK][jj][t] = a;
        }
    }
}

template<int BANK>
__device__ __forceinline__ void
consume(f32x4 (&acc)[4][2], const short8 (&A)[2][2][4], const short8 (&B)[2][2][2]) {
    #pragma unroll
    for (int jj = 0; jj < 2; jj++) {
        #pragma unroll
        for (int t = 0; t < 4; t++) {
            acc[t][0] = __builtin_amdgcn_mfma_f32_16x16x32_bf16(A[BANK][jj][t], B[BANK][jj][0], acc[t][0], 0, 0, 0);
            acc[t][1] = __builtin_amdgcn_mfma_f32_16x16x32_bf16(A[BANK][jj][t], B[BANK][jj][1], acc[t][1], 0, 0, 0);
        }
    }
}

// K2: gather-conv. Wave = 4 tiles of 16 voxels. Taps padded to 128, processed
// as 8 windows x 8 groups(2 taps), double-buffered refill distance 2.
__global__ __launch_bounds__(256, 2) void
k_conv(const unsigned short* __restrict__ xb, const int* __restrict__ nbr,
       const unsigned short* __restrict__ wf, float* __restrict__ co,
       float* __restrict__ stats) {
    const int lane = threadIdx.x & 63;
    const int wv = threadIdx.x >> 6;
    const int m = lane & 15;
    const int q = lane >> 4;
    const int q4 = q * 4;
    const int vbase = (blockIdx.x * 4 + wv) * 64;

    f32x4 acc[4][2];
    #pragma unroll
    for (int t = 0; t < 4; t++)
        #pragma unroll
        for (int h = 0; h < 2; h++)
            acc[t][h] = f32x4{0.f, 0.f, 0.f, 0.f};

    bool tval[4];
    int rbase[4];
    #pragma unroll
    for (int t = 0; t < 4; t++) {
        tval[t] = (vbase + t * 16) < NV;
        rbase[t] = tval[t] ? (vbase + t * 16 + m) * KT : 0;
    }

    short8 A[2][2][4];
    short8 B[2][2][2];
    int4a nb4[4], nbn4[4];

    load_nb4(0, nbr, rbase, q4, nb4);
    refill<0, 0>(A, B, 0, nb4, xb, wf, m, q, lane);
    refill<1, 2>(A, B, 2, nb4, xb, wf, m, q, lane);

    for (int w = 0; w < 8; w++) {
        const int kb = w * 16;
        if (w < 7) load_nb4(w + 1, nbr, rbase, q4, nbn4);
        consume<0>(acc, A, B); refill<0, 4>(A, B, kb + 4, nb4, xb, wf, m, q, lane);
        consume<1>(acc, A, B); refill<1, 6>(A, B, kb + 6, nb4, xb, wf, m, q, lane);
        consume<0>(acc, A, B); refill<0, 8>(A, B, kb + 8, nb4, xb, wf, m, q, lane);
        consume<1>(acc, A, B); refill<1, 10>(A, B, kb + 10, nb4, xb, wf, m, q, lane);
        consume<0>(acc, A, B); refill<0, 12>(A, B, kb + 12, nb4, xb, wf, m, q, lane);
        consume<1>(acc, A, B); refill<1, 14>(A, B, kb + 14, nb4, xb, wf, m, q, lane);
        consume<0>(acc, A, B); refill<0, 0>(A, B, kb + 16, nbn4, xb, wf, m, q, lane);
        consume<1>(acc, A, B); refill<1, 2>(A, B, kb + 18, nbn4, xb, wf, m, q, lane);
        #pragma unroll
        for (int t = 0; t < 4; t++)
            nb4[t] = nbn4[t];
    }

    float s0 = 0.f, s1 = 0.f, q0 = 0.f, q1 = 0.f;
    #pragma unroll
    for (int t = 0; t < 4; t++) {
        if (!tval[t]) continue;
        int v0 = vbase + t * 16 + q * 4;
        #pragma unroll
        for (int r = 0; r < 4; r++) {
            float a0 = acc[t][0][r], a1 = acc[t][1][r];
            // nt: co is written once here, read much later by k_epi; keep it
            // out of L2/L3 so xb stays resident.
            __builtin_nontemporal_store(a0, co + (size_t)(v0 + r) * CH + m);
            __builtin_nontemporal_store(a1, co + (size_t)(v0 + r) * CH + 16 + m);
            s0 += a0; q0 += a0 * a0;
            s1 += a1; q1 += a1 * a1;
        }
    }
    s0 += __shfl_xor(s0, 16); s0 += __shfl_xor(s0, 32);
    s1 += __shfl_xor(s1, 16); s1 += __shfl_xor(s1, 32);
    q0 += __shfl_xor(q0, 16); q0 += __shfl_xor(q0, 32);
    q1 += __shfl_xor(q1, 16); q1 += __shfl_xor(q1, 32);
    if (q == 0) {
        atomicAdd(&stats[m],      s0);
        atomicAdd(&stats[16 + m], s1);
        atomicAdd(&stats[32 + m], q0);
        atomicAdd(&stats[48 + m], q1);
    }
}

// K3: finalize BN scale/shift. stats[64..95]=scale, stats[96..127]=shift.
__global__ void k_final(const float* __restrict__ gamma, const float* __restrict__ beta,
                        float* __restrict__ stats) {
    int c = threadIdx.x;
    if (c < CH) {
        float mean = stats[c] * (1.0f / NV);
        float var = stats[32 + c] * (1.0f / NV) - mean * mean;
        float sc = gamma[c] * rsqrtf(var + EPSBN);
        stats[64 + c] = sc;
        stats[96 + c] = beta[c] - mean * sc;
    }
}

// K4: in-place BN + ELU + MFMA linear on d_out. Wave = one 16-voxel tile/iter.
__global__ __launch_bounds__(256) void
k_epi(float* __restrict__ io, const unsigned short* __restrict__ wl,
      const float* __restrict__ blin, const float* __restrict__ stats) {
    const int lane = threadIdx.x & 63;
    const int wv = threadIdx.x >> 6;
    const int m = lane & 15;
    const int q = lane >> 4;

    short8 wl0 = *(const short8*)(wl + (size_t)lane * 8);
    short8 wl1 = *(const short8*)(wl + (size_t)(64 + lane) * 8);
    float ssc8[8], ssh8[8];
    #pragma unroll
    for (int j = 0; j < 8; j++) {
        ssc8[j] = stats[64 + q * 8 + j];
        ssh8[j] = stats[96 + q * 8 + j];
    }
    float bias0 = blin[m];
    float bias1 = blin[16 + m];

    const int wstep = gridDim.x * 4;
    for (int tile = blockIdx.x * 4 + wv; tile < NTILES; tile += wstep) {
        const int v0 = tile * 16;
        const float* p = io + (size_t)(v0 + m) * CH + q * 8;
        float4 e0 = *(const float4*)p;
        float4 e1 = *(const float4*)(p + 4);
        float e[8] = {e0.x, e0.y, e0.z, e0.w, e1.x, e1.y, e1.z, e1.w};
        short8 a;
        #pragma unroll
        for (int j = 0; j < 8; j++) {
            float f = e[j] * ssc8[j] + ssh8[j];
            f = f > 0.0f ? f : (__expf(f) - 1.0f);      // ELU alpha=1
            a[j] = (short)f2bf(f);
        }
        f32x4 z = {0.f, 0.f, 0.f, 0.f};
        f32x4 d0 = __builtin_amdgcn_mfma_f32_16x16x32_bf16(a, wl0, z, 0, 0, 0);
        f32x4 d1 = __builtin_amdgcn_mfma_f32_16x16x32_bf16(a, wl1, z, 0, 0, 0);
        #pragma unroll
        for (int r = 0; r < 4; r++) {
            io[(size_t)(v0 + q * 4 + r) * CH + m]      = d0[r] + bias0;
            io[(size_t)(v0 + q * 4 + r) * CH + 16 + m] = d1[r] + bias1;
        }
    }
}

extern "C" void kernel_launch(void* const* d_in, const int* in_sizes, int n_in,
                              void* d_out, int out_size, void* d_ws, size_t ws_size,
                              hipStream_t stream) {
    const float* x     = (const float*)d_in[0];
    const int*   nbr   = (const int*)d_in[1];
    const float* Wc    = (const float*)d_in[2];
    // d_in[3] = b_conv: canceled by BN mean subtraction.
    const float* gamma = (const float*)d_in[4];
    const float* beta  = (const float*)d_in[5];
    const float* Wlin  = (const float*)d_in[6];
    const float* blin  = (const float*)d_in[7];
    float* out = (float*)d_out;

    char* ws = (char*)d_ws;
    unsigned short* xb = (unsigned short*)ws;                               // 32 MB
    size_t off = (size_t)NV * CH * 2;
    unsigned short* wf = (unsigned short*)(ws + off);                       // 256 KB
    off += (size_t)KT * 128 * 8 * 2;
    unsigned short* wl = (unsigned short*)(ws + off);                       // 2 KB
    off += 128 * 8 * 2;
    float* stats = (float*)(ws + off);                                      // 512 B

    int prep_blocks = (int)(((size_t)NV * CH / 8 + 255) / 256);             // 7813
    hipLaunchKernelGGL(k_prep, dim3(prep_blocks), dim3(256), 0, stream,
                       x, Wc, Wlin, xb, wf, wl, stats);
    hipLaunchKernelGGL(k_conv, dim3((NV + 255) / 256), dim3(256), 0, stream,
                       xb, nbr, wf, out, stats);
    hipLaunchKernelGGL(k_final, dim3(1), dim3(64), 0, stream, gamma, beta, stats);
    hipLaunchKernelGGL(k_epi, dim3(1024), dim3(256), 0, stream, out, wl, blin, stats);
}